// Round 2
// baseline (844.225 us; speedup 1.0000x reference)
//
#include <hip/hip_runtime.h>

// LatticeSuperpixel: B=8, C=20, H=W=512, 32x32 seeds, 16x16 cells, 4 levels.
#define NB 8
#define NC 20
#define NH 512
#define NW 512
#define NS 1024           // 32*32 seeds
#define HW (NH * NW)
#define SEEDS_ELEMS (NB * NS * NC)   // 163840
#define DENOM_ELEMS (NB * NS)        // 8192

__device__ __forceinline__ int clampi(int v, int lo, int hi) {
    return v < lo ? lo : (v > hi ? hi : v);
}

__constant__ int c_dyo[9] = {-1, -1, -1, 0, 0, 0, 1, 1, 1};
__constant__ int c_dxo[9] = {-1, 0, 1, -1, 0, 1, -1, 0, 1};

// ---------------------------------------------------------------------------
// Kernel 1: seed init = mean over each 16x16 patch, per channel.
// 160 threads: (c in 0..19, s in 0..7); thread sums 8 float4 pixel-quads.
// ---------------------------------------------------------------------------
__global__ __launch_bounds__(160) void k_seed_init(const float* __restrict__ x,
                                                   float* __restrict__ seeds) {
    const int tt = threadIdx.x;           // < 160
    const int cell = blockIdx.x;
    const int b = blockIdx.y;
    const int cy = cell >> 5, cx = cell & 31;
    const int c = tt >> 3, s = tt & 7;

    const float* xb = x + (size_t)b * (NC * HW) + (size_t)c * HW
                        + (size_t)(cy << 4) * NW + (cx << 4);
    float acc = 0.f;
#pragma unroll
    for (int k = 0; k < 8; ++k) {
        const int row = (k << 1) + (s >> 2);
        const int col = (s & 3) << 2;
        const float4 v = *reinterpret_cast<const float4*>(xb + row * NW + col);
        acc += v.x + v.y + v.z + v.w;
    }
    // fold the 8 strips (s bits = lane bits 0..2)
    acc += __shfl_xor(acc, 1, 64);
    acc += __shfl_xor(acc, 2, 64);
    acc += __shfl_xor(acc, 4, 64);
    if (s == 0)
        seeds[((size_t)(b << 10) + cell) * NC + c] = acc * (1.0f / 256.0f);
}

// ---------------------------------------------------------------------------
// Kernel 2: one assignment iteration + seed-update accumulation.
// Phase 1 (256 thr = 1 pixel each): dist vs 9 neighbor seeds, softmax -> qs_t.
// Phase 2 (168 thr = (c in 0..20, s in 0..7)): register-tiled outer product
//   numer[9][20] (+ denom via pseudo-channel c==20), x re-read from L1/L2.
// ---------------------------------------------------------------------------
__global__ __launch_bounds__(256) void k_iter(const float* __restrict__ x,
                                              const float* __restrict__ seeds,
                                              float* __restrict__ numer,
                                              float* __restrict__ denom) {
    __shared__ float s_lds[9][NC];
    __shared__ float s_sn[9];
    __shared__ __align__(16) float qs_t[9][260];   // [offset][pixel], 16B-aligned rows
    __shared__ float red[168][13];                 // stride 13: coprime with 32

    const int t = threadIdx.x;
    const int cell = blockIdx.x;
    const int b = blockIdx.y;
    const int cy = cell >> 5, cx = cell & 31;

    // ---- phase 1: per-pixel distances + softmax ----
    const int py = (cy << 4) + (t >> 4);
    const int px = (cx << 4) + (t & 15);
    const float* xp = x + (size_t)b * (NC * HW) + (size_t)py * NW + px;
    float xv[NC];
#pragma unroll
    for (int c = 0; c < NC; ++c) xv[c] = xp[(size_t)c * HW];

    if (t < 180) {
        const int o = t / 20, c = t - o * 20;
        const int ny = clampi(cy + c_dyo[o], 0, 31);
        const int nx = clampi(cx + c_dxo[o], 0, 31);
        s_lds[o][c] = seeds[((size_t)(b << 10) + (ny << 5) + nx) * NC + c];
    }
    __syncthreads();
    if (t < 9) {
        float s = 0.f;
#pragma unroll
        for (int c = 0; c < NC; ++c) s += s_lds[t][c] * s_lds[t][c];
        s_sn[t] = s;
    }
    __syncthreads();

    float d[9];
#pragma unroll
    for (int o = 0; o < 9; ++o) {
        float ip = 0.f;
#pragma unroll
        for (int c = 0; c < NC; ++c) ip += xv[c] * s_lds[o][c];
        d[o] = s_sn[o] - 2.0f * ip;
    }
    float m = d[0];
#pragma unroll
    for (int o = 1; o < 9; ++o) m = fminf(m, d[o]);
    float w[9];
    float wsum = 0.f;
#pragma unroll
    for (int o = 0; o < 9; ++o) {
        w[o] = __expf(m - d[o]);
        wsum += w[o];
    }
    const float inv = 1.0f / wsum;
#pragma unroll
    for (int o = 0; o < 9; ++o) qs_t[o][t] = w[o] * inv;  // banks (4o+t)%32: clean
    __syncthreads();

    // ---- phase 2: acc[9] per (c,s), 8 pixel-quads each ----
    if (t < 168) {
        const int c = t >> 3, s = t & 7;   // c in 0..20 (20 == denom channel)
        float4 acc[9];
#pragma unroll
        for (int o = 0; o < 9; ++o) acc[o] = make_float4(0.f, 0.f, 0.f, 0.f);

        const float* xb = x + (size_t)b * (NC * HW) + (size_t)c * HW
                            + (size_t)(cy << 4) * NW + (cx << 4);
        const int row0 = s >> 2, col = (s & 3) << 2;
#pragma unroll
        for (int k = 0; k < 8; ++k) {
            const int qd = (k << 3) + s;          // pixel-quad id, pixels 4qd..4qd+3
            float4 f4;
            if (c < NC) {
                f4 = *reinterpret_cast<const float4*>(xb + ((k << 1) + row0) * NW + col);
            } else {
                f4 = make_float4(1.f, 1.f, 1.f, 1.f);
            }
#pragma unroll
            for (int o = 0; o < 9; ++o) {
                const float4 q4 = *reinterpret_cast<const float4*>(&qs_t[o][qd << 2]);
                acc[o].x += q4.x * f4.x;
                acc[o].y += q4.y * f4.y;
                acc[o].z += q4.z * f4.z;
                acc[o].w += q4.w * f4.w;
            }
        }
#pragma unroll
        for (int o = 0; o < 9; ++o)
            red[t][o] = (acc[o].x + acc[o].y) + (acc[o].z + acc[o].w);
    }
    __syncthreads();

    // ---- fold 8 strips, atomically add to global ----
    if (t < 189) {
        const int c = t / 9, o = t - c * 9;   // c in 0..20
        float v = 0.f;
#pragma unroll
        for (int s = 0; s < 8; ++s) v += red[(c << 3) + s][o];
        const int ny = clampi(cy + c_dyo[o], 0, 31);
        const int nx = clampi(cx + c_dxo[o], 0, 31);
        const size_t sidx = (size_t)(b << 10) + (ny << 5) + nx;
        if (c < NC) atomicAdd(&numer[sidx * NC + c], v);
        else        atomicAdd(&denom[sidx], v);
    }
}

// ---------------------------------------------------------------------------
// Kernel 3: seeds = numer / (denom + eps)
// ---------------------------------------------------------------------------
__global__ __launch_bounds__(256) void k_div(float* __restrict__ seeds,
                                             const float* __restrict__ numer,
                                             const float* __restrict__ denom) {
    const int i = blockIdx.x * 256 + threadIdx.x;  // < 163840
    seeds[i] = numer[i] / (denom[i / NC] + 1e-8f);
}

// ---------------------------------------------------------------------------
// Kernel 4: final assignment pass -> write Q (B, 9, H, W)
// ---------------------------------------------------------------------------
__global__ __launch_bounds__(256) void k_final(const float* __restrict__ x,
                                               const float* __restrict__ seeds,
                                               float* __restrict__ out) {
    __shared__ float s_lds[9][NC];
    __shared__ float s_sn[9];

    const int t = threadIdx.x;
    const int cell = blockIdx.x;
    const int b = blockIdx.y;
    const int cy = cell >> 5, cx = cell & 31;

    const int py = (cy << 4) + (t >> 4);
    const int px = (cx << 4) + (t & 15);
    const float* xp = x + (size_t)b * (NC * HW) + (size_t)py * NW + px;
    float xv[NC];
#pragma unroll
    for (int c = 0; c < NC; ++c) xv[c] = xp[(size_t)c * HW];

    if (t < 180) {
        const int o = t / 20, c = t - o * 20;
        const int ny = clampi(cy + c_dyo[o], 0, 31);
        const int nx = clampi(cx + c_dxo[o], 0, 31);
        s_lds[o][c] = seeds[((size_t)(b << 10) + (ny << 5) + nx) * NC + c];
    }
    __syncthreads();
    if (t < 9) {
        float s = 0.f;
#pragma unroll
        for (int c = 0; c < NC; ++c) s += s_lds[t][c] * s_lds[t][c];
        s_sn[t] = s;
    }
    __syncthreads();

    float d[9];
#pragma unroll
    for (int o = 0; o < 9; ++o) {
        float ip = 0.f;
#pragma unroll
        for (int c = 0; c < NC; ++c) ip += xv[c] * s_lds[o][c];
        d[o] = s_sn[o] - 2.0f * ip;
    }
    float m = d[0];
#pragma unroll
    for (int o = 1; o < 9; ++o) m = fminf(m, d[o]);
    float w[9];
    float wsum = 0.f;
#pragma unroll
    for (int o = 0; o < 9; ++o) {
        w[o] = __expf(m - d[o]);
        wsum += w[o];
    }
    const float inv = 1.0f / wsum;
#pragma unroll
    for (int o = 0; o < 9; ++o) {
        out[(((size_t)b * 9 + o) * NH + py) * NW + px] = w[o] * inv;
    }
}

// ---------------------------------------------------------------------------
extern "C" void kernel_launch(void* const* d_in, const int* in_sizes, int n_in,
                              void* d_out, int out_size, void* d_ws, size_t ws_size,
                              hipStream_t stream) {
    const float* x = (const float*)d_in[0];
    float* out = (float*)d_out;

    float* seeds = (float*)d_ws;                 // 163840 floats
    float* numer = seeds + SEEDS_ELEMS;          // 163840 floats
    float* denom = numer + SEEDS_ELEMS;          // 8192 floats

    const dim3 grid(NS, NB);  // 1024 cells x 8 batches
    k_seed_init<<<grid, 160, 0, stream>>>(x, seeds);

    for (int it = 0; it < 3; ++it) {
        hipMemsetAsync(numer, 0, (SEEDS_ELEMS + DENOM_ELEMS) * sizeof(float), stream);
        k_iter<<<grid, 256, 0, stream>>>(x, seeds, numer, denom);
        k_div<<<SEEDS_ELEMS / 256, 256, 0, stream>>>(seeds, numer, denom);
    }
    k_final<<<grid, 256, 0, stream>>>(x, seeds, out);
}